// Round 4
// baseline (66.944 us; speedup 1.0000x reference)
//
#include <hip/hip_runtime.h>
#include <stdint.h>

#define D_IN    2048
#define NT      15
#define PPT     14359      // 7*(2048+1) + 8*2
#define NVALID  60         // 15 trees * 4 used internal nodes

typedef __bf16   bf16x8 __attribute__((ext_vector_type(8)));
typedef float    f32x4  __attribute__((ext_vector_type(4)));
typedef uint32_t u32x4  __attribute__((ext_vector_type(4)));

#define WAITV8 asm volatile("s_waitcnt vmcnt(8)" ::: "memory")
#define WAITV0 asm volatile("s_waitcnt vmcnt(0)" ::: "memory")
#define WAITL0 asm volatile("s_waitcnt lgkmcnt(0)" ::: "memory")
#define SCHEDB __builtin_amdgcn_sched_barrier(0)

// ---------------- asm helpers -------------------------------------------------
__device__ __forceinline__ f32x4 gload4(const float* p) {
  f32x4 r;
  asm volatile("global_load_dwordx4 %0, %1, off" : "=v"(r) : "v"(p) : "memory");
  return r;
}
__device__ __forceinline__ u32x4 dsread16(uint32_t addr) {
  u32x4 r;
  asm volatile("ds_read_b128 %0, %1" : "=v"(r) : "v"(addr) : "memory");
  return r;
}
__device__ __forceinline__ void dswrite16(uint32_t addr, u32x4 v) {
  asm volatile("ds_write_b128 %0, %1" :: "v"(addr), "v"(v) : "memory");
}

// pack two floats -> (hi bf16 pair, lo bf16 pair); lo = residual of truncation
#define CVT_PAIR(P, Q, HW, LW) do {                                   \
    uint32_t _up = __float_as_uint(P), _uq = __float_as_uint(Q);      \
    uint32_t _mp = _up & 0xFFFF0000u, _mq = _uq & 0xFFFF0000u;        \
    (HW) = (_up >> 16) | _mq;                                         \
    float _lp = (P) - __uint_as_float(_mp);                           \
    float _lq = (Q) - __uint_as_float(_mq);                           \
    (LW) = (__float_as_uint(_lp) >> 16) |                             \
           (__float_as_uint(_lq) & 0xFFFF0000u);                      \
  } while (0)

// 8 floats (two f32x4) -> hi u32x4 (8 bf16) + lo u32x4 (8 bf16)
__device__ __forceinline__ void cvt8(const f32x4 A, const f32x4 B,
                                     u32x4& hi, u32x4& lo) {
  CVT_PAIR(A[0], A[1], hi[0], lo[0]);
  CVT_PAIR(A[2], A[3], hi[1], lo[1]);
  CVT_PAIR(B[0], B[1], hi[2], lo[2]);
  CVT_PAIR(B[2], B[3], hi[3], lo[3]);
}

// One K-step (BK=64). Protocol (counted vmcnt, one barrier/iter, 3 LDS bufs):
//   barrier
//   ds_read 16 B-frags of buf[BUF]; cvt A(t) (landed: prev iter's end-wait)
//   lgkmcnt(0)                      -> my reads done before anyone's next write
//   issue W(t+2) (4 ld) + A(t+2) (4 ld)          [in-flight: t+1, t+2 = 16]
//   24 MFMA
//   vmcnt(8) -> W(t+1),A(t+1) landed; cvt W(t+1) hi/lo; ds_write buf[WBUF];
//   lgkmcnt(0)                      -> writes visible before next barrier
#define ITERATION(tt, BUF, WBUF, RC, WA, WB, ISSUE, ENDSTAGE, ENDV0)           \
  {                                                                            \
    __builtin_amdgcn_s_barrier();                                              \
    const uint32_t bb = sbase + (BUF) * 16384 + l16;                           \
    u32x4 bfr[16];                                                             \
    _Pragma("unroll")                                                          \
    for (int q = 0; q < 16; ++q) bfr[q] = dsread16(bb + q * 1024);             \
    u32x4 ah0, al0, ah1, al1;                                                  \
    cvt8(RC[0], RC[1], ah0, al0);                                              \
    cvt8(RC[2], RC[3], ah1, al1);                                              \
    WAITL0; SCHEDB;                                                            \
    if (ISSUE) {                                                               \
      const int t2 = (tt) + 2;                                                 \
      WA[0] = gload4(wp0 + t2 * 64);  WA[1] = gload4(wp0 + t2 * 64 + 4);       \
      WA[2] = gload4(wp1 + t2 * 64);  WA[3] = gload4(wp1 + t2 * 64 + 4);       \
      const float* ap = xbase + t2 * 64;                                       \
      RC[0] = gload4(ap);      RC[1] = gload4(ap + 4);                         \
      RC[2] = gload4(ap + 32); RC[3] = gload4(ap + 36);                        \
    }                                                                          \
    _Pragma("unroll")                                                          \
    for (int f = 0; f < 4; ++f) {                                              \
      bf16x8 bh = __builtin_bit_cast(bf16x8, bfr[f * 2]);                      \
      bf16x8 bl = __builtin_bit_cast(bf16x8, bfr[f * 2 + 1]);                  \
      bf16x8 Ah = __builtin_bit_cast(bf16x8, ah0);                             \
      bf16x8 Al = __builtin_bit_cast(bf16x8, al0);                             \
      acc[f] = __builtin_amdgcn_mfma_f32_16x16x32_bf16(Ah, bh, acc[f], 0,0,0); \
      acc[f] = __builtin_amdgcn_mfma_f32_16x16x32_bf16(Al, bh, acc[f], 0,0,0); \
      acc[f] = __builtin_amdgcn_mfma_f32_16x16x32_bf16(Ah, bl, acc[f], 0,0,0); \
    }                                                                          \
    _Pragma("unroll")                                                          \
    for (int f = 0; f < 4; ++f) {                                              \
      bf16x8 bh = __builtin_bit_cast(bf16x8, bfr[8 + f * 2]);                  \
      bf16x8 bl = __builtin_bit_cast(bf16x8, bfr[8 + f * 2 + 1]);              \
      bf16x8 Ah = __builtin_bit_cast(bf16x8, ah1);                             \
      bf16x8 Al = __builtin_bit_cast(bf16x8, al1);                             \
      acc[f] = __builtin_amdgcn_mfma_f32_16x16x32_bf16(Ah, bh, acc[f], 0,0,0); \
      acc[f] = __builtin_amdgcn_mfma_f32_16x16x32_bf16(Al, bh, acc[f], 0,0,0); \
      acc[f] = __builtin_amdgcn_mfma_f32_16x16x32_bf16(Ah, bl, acc[f], 0,0,0); \
    }                                                                          \
    if (ENDSTAGE) {                                                            \
      if (ENDV0) { WAITV0; } else { WAITV8; }                                  \
      SCHEDB;                                                                  \
      f32x4 w2 = WB[2] * vmask, w3 = WB[3] * vmask;                            \
      u32x4 h0, l0, h1, l1;                                                    \
      cvt8(WB[0], WB[1], h0, l0);                                              \
      cvt8(w2, w3, h1, l1);                                                    \
      const uint32_t wb_ = sbase + (WBUF) * 16384 + w4096 + l16;               \
      dswrite16(wb_,        h0);  dswrite16(wb_ + 1024, l0);                   \
      dswrite16(wb_ + 2048, h1);  dswrite16(wb_ + 3072, l1);                   \
      WAITL0; SCHEDB;                                                          \
    }                                                                          \
  }

__global__ __launch_bounds__(256) void tree_fused(
    const float* __restrict__ x,
    const float* __restrict__ tp,
    const float* __restrict__ tw,
    float* __restrict__ out)
{
  __shared__ __align__(1024) unsigned char sB[3 * 16384];   // B hi/lo triple buffer
  __shared__ float strips[4][16][65];                       // per-wave epilogue strip
  __shared__ float sBias[64];
  __shared__ float sCoef[160];

  const int tid = threadIdx.x;
  const int w   = tid >> 6;        // wave 0..3
  const int l   = tid & 63;
  const int rl  = l & 15;
  const int g   = l >> 4;
  const int l16 = l * 16;
  const int w4096 = w * 4096;

  // ---- prologue A: per-block coef/bias (redundant, trivial) ----
  if (tid < 64) {
    float b = 0.0f;
    if (tid < NVALID) { int t = tid >> 2, i = tid & 3; b = tp[t * PPT + 14336 + i]; }
    sBias[tid] = b;
  } else if (tid < 64 + NT) {
    int t = tid - 64;
    const float* ll = tp + t * PPT + 14343;  // leaf_logits [8][2]
    float d0[8], d1[8];
#pragma unroll
    for (int le = 0; le < 8; ++le) {
      float aa = ll[2 * le], bb = ll[2 * le + 1];
      float m = fmaxf(aa, bb);
      float e0 = __expf(aa - m), e1 = __expf(bb - m);
      float inv = 1.0f / (e0 + e1);
      d0[le] = e0 * inv; d1[le] = e1 * inv;
    }
    float ww = tw[t];
    float* c = sCoef + t * 10;
    c[0] = ww * (d0[0] + d0[2] + d0[4] + d0[6]);
    c[1] = ww * (d1[0] + d1[2] + d1[4] + d1[6]);
    c[2] = ww * (d0[1] - d0[2]);
    c[3] = ww * (d1[1] - d1[2]);
    c[4] = ww * (d0[3] - d0[4]);
    c[5] = ww * (d1[3] - d1[4]);
    c[6] = ww * (d0[5] - d0[6]);
    c[7] = ww * (d1[5] - d1[6]);
    c[8] = ww * d0[7];
    c[9] = ww * d1[7];
  }
  __syncthreads();   // drains all vmem/lds of prologue A before counted protocol

  // ---- W gather setup: wave w owns frags (h=w>>1, f=f0,f0+1), rows n=16f+rl ----
  const int h  = w >> 1;
  const int f0 = 2 * (w & 1);
  const int n0 = 16 * f0 + rl;           // <= 47, always valid
  const int n1 = n0 + 16;                // f0+1; invalid when >= 60 (w odd, rl>=12)
  const float vmask = (n1 < NVALID) ? 1.0f : 0.0f;
  const int coloff = h * 32 + g * 8;     // k offset within slab row
  const float* wp0 = tp + (size_t)(n0 >> 2) * PPT + (n0 & 3) * D_IN + coloff;
  const float* wp1r = tp + (size_t)(n1 >> 2) * PPT + (n1 & 3) * D_IN + coloff;
  const float* wp1 = (n1 < NVALID) ? wp1r : tp;   // clamp OOB lanes into tp[0..]

  const int rowTile = blockIdx.x * 64 + w * 16;
  const float* xbase = x + (size_t)(rowTile + rl) * D_IN + g * 8;
  const uint32_t sbase = (uint32_t)(uintptr_t)&sB[0];

  f32x4 acc[4] = {};
  f32x4 rA[4], rB[4];            // A regs, parity t%2
  f32x4 wWa[4], wWb[4];          // W regs, parity t%2

  // ---- prologue B: issue W(0),A(0),W(1),A(1); convert+write W(0)->buf0 ----
  {
    wWa[0] = gload4(wp0);      wWa[1] = gload4(wp0 + 4);
    wWa[2] = gload4(wp1);      wWa[3] = gload4(wp1 + 4);
    rA[0] = gload4(xbase);      rA[1] = gload4(xbase + 4);
    rA[2] = gload4(xbase + 32); rA[3] = gload4(xbase + 36);
    wWb[0] = gload4(wp0 + 64);  wWb[1] = gload4(wp0 + 68);
    wWb[2] = gload4(wp1 + 64);  wWb[3] = gload4(wp1 + 68);
    rB[0] = gload4(xbase + 64); rB[1] = gload4(xbase + 68);
    rB[2] = gload4(xbase + 96); rB[3] = gload4(xbase + 100);
    WAITV8; SCHEDB;                       // W(0),A(0) landed
    f32x4 w2 = wWa[2] * vmask, w3 = wWa[3] * vmask;
    u32x4 h0, l0, h1, l1;
    cvt8(wWa[0], wWa[1], h0, l0);
    cvt8(w2, w3, h1, l1);
    const uint32_t wb_ = sbase + w4096 + l16;
    dswrite16(wb_,        h0);  dswrite16(wb_ + 1024, l0);
    dswrite16(wb_ + 2048, h1);  dswrite16(wb_ + 3072, l1);
    WAITL0; SCHEDB;
  }

  // ---- main loop: period 6 (buf %3 x reg parity %2), 30 iters + 2 tail ----
  for (int tb = 0; tb < 30; tb += 6) {
    ITERATION(tb + 0, 0, 1, rA, wWa, wWb, 1, 1, 0);
    ITERATION(tb + 1, 1, 2, rB, wWb, wWa, 1, 1, 0);
    ITERATION(tb + 2, 2, 0, rA, wWa, wWb, 1, 1, 0);
    ITERATION(tb + 3, 0, 1, rB, wWb, wWa, 1, 1, 0);
    ITERATION(tb + 4, 1, 2, rA, wWa, wWb, 1, 1, 0);
    ITERATION(tb + 5, 2, 0, rB, wWb, wWa, 1, 1, 0);
  }
  ITERATION(30, 0, 1, rA, wWa, wWb, 0, 1, 1);   // end: vmcnt(0), write W(31)->buf1
  ITERATION(31, 1, 2, rB, wWb, wWa, 0, 0, 0);   // pure compute tail

  // ---- epilogue: per-wave strip transpose + folded tree math ----
#pragma unroll
  for (int f = 0; f < 4; ++f)
#pragma unroll
    for (int r = 0; r < 4; ++r)
      strips[w][4 * g + r][16 * f + rl] = acc[f][r];
  WAITL0;

  float o0 = 0.0f, o1 = 0.0f;
#pragma unroll
  for (int jt = 0; jt < 4; ++jt) {
    int t = g + 4 * jt;
    if (t < NT) {
      const float* cf = sCoef + t * 10;
      float dd[4];
#pragma unroll
      for (int i = 0; i < 4; ++i) {
        float z = strips[w][rl][4 * t + i] + sBias[4 * t + i];
        dd[i] = 1.0f / (1.0f + __expf(-z));
      }
      float s = 1.0f / (4.0f + dd[3] + 1e-8f);
      o0 += s * (cf[0] + dd[0] * cf[2] + dd[1] * cf[4] + dd[2] * cf[6] + dd[3] * cf[8]);
      o1 += s * (cf[1] + dd[0] * cf[3] + dd[1] * cf[5] + dd[2] * cf[7] + dd[3] * cf[9]);
    }
  }
  o0 += __shfl_xor(o0, 16); o0 += __shfl_xor(o0, 32);
  o1 += __shfl_xor(o1, 16); o1 += __shfl_xor(o1, 32);
  if (l < 16) {
    ((float2*)out)[rowTile + rl] = make_float2(o0, o1);
  }
}

// ---------------- launch ------------------------------------------------------
extern "C" void kernel_launch(void* const* d_in, const int* in_sizes, int n_in,
                              void* d_out, int out_size, void* d_ws, size_t ws_size,
                              hipStream_t stream) {
  (void)in_sizes; (void)n_in; (void)out_size; (void)d_ws; (void)ws_size;
  const float* x  = (const float*)d_in[0];
  const float* tp = (const float*)d_in[1];
  const float* tw = (const float*)d_in[2];
  float* out = (float*)d_out;

  tree_fused<<<512, 256, 0, stream>>>(x, tp, tw, out);
}

// Round 5
// 56.293 us; speedup vs baseline: 1.1892x; 1.1892x over previous
//
#include <hip/hip_runtime.h>
#include <stdint.h>

#define D_IN    2048
#define NT      15
#define PPT     14359      // 7*(2048+1) + 8*2
#define NVALID  60         // 15 trees * 4 used internal nodes

typedef __bf16   bf16x8 __attribute__((ext_vector_type(8)));
typedef float    f32x4  __attribute__((ext_vector_type(4)));
typedef uint32_t u32x4  __attribute__((ext_vector_type(4)));

#define WAITV(n) asm volatile("s_waitcnt vmcnt(" #n ")" ::: "memory")
#define WAITL0   asm volatile("s_waitcnt lgkmcnt(0)" ::: "memory")
#define SCHEDB   __builtin_amdgcn_sched_barrier(0)

// pack two floats -> (hi bf16 pair, lo bf16 pair); lo = residual of truncation
#define CVT_PAIR(P, Q, HW, LW) do {                                   \
    uint32_t _up = __float_as_uint(P), _uq = __float_as_uint(Q);      \
    uint32_t _mp = _up & 0xFFFF0000u, _mq = _uq & 0xFFFF0000u;        \
    (HW) = (_up >> 16) | _mq;                                         \
    float _lp = (P) - __uint_as_float(_mp);                           \
    float _lq = (Q) - __uint_as_float(_mq);                           \
    (LW) = (__float_as_uint(_lp) >> 16) |                             \
           (__float_as_uint(_lq) & 0xFFFF0000u);                      \
  } while (0)

__device__ __forceinline__ void cvt8(const f32x4 A, const f32x4 B,
                                     u32x4& hi, u32x4& lo) {
  CVT_PAIR(A[0], A[1], hi[0], lo[0]);
  CVT_PAIR(A[2], A[3], hi[1], lo[1]);
  CVT_PAIR(B[0], B[1], hi[2], lo[2]);
  CVT_PAIR(B[2], B[3], hi[3], lo[3]);
}

// ---------------- prep: split W into bf16 hi/lo in MFMA-B fragment order ----
// One thread per 8 k's: read 8 floats of row n, write 16B hi + 16B lo chunks.
// frag bytes: ((ks*4+f)*2+part)*1024 + lane*16, lane=(n&15)|(((k>>3)&3)<<4)
__global__ __launch_bounds__(256) void prep_split(const float* __restrict__ tp,
                                                  const float* __restrict__ tw,
                                                  unsigned short* __restrict__ bsp,
                                                  float* __restrict__ bias,
                                                  float* __restrict__ coef) {
  const int n  = blockIdx.x;        // 0..63 (row of W-pad)
  const int j  = threadIdx.x;       // 0..255
  const int k0 = j * 8;
  f32x4 v0 = {0,0,0,0}, v1 = {0,0,0,0};
  if (n < NVALID) {
    const float* src = tp + (size_t)(n >> 2) * PPT + (n & 3) * D_IN + k0;
#pragma unroll
    for (int q = 0; q < 4; ++q) v0[q] = src[q];
#pragma unroll
    for (int q = 0; q < 4; ++q) v1[q] = src[4 + q];
  }
  u32x4 hi, lo;
  cvt8(v0, v1, hi, lo);
  const int ks = k0 >> 5, f = n >> 4;
  const int lane = (n & 15) | (((k0 >> 3) & 3) << 4);
  char* bb = (char*)bsp + ((size_t)(ks * 4 + f) * 2) * 1024 + (size_t)lane * 16;
  *(u32x4*)(bb)        = hi;
  *(u32x4*)(bb + 1024) = lo;

  if (blockIdx.x == 0) {
    int tid = threadIdx.x;
    if (tid < 64) {
      float b = 0.0f;
      if (tid < NVALID) { int t = tid >> 2, i = tid & 3; b = tp[t * PPT + 14336 + i]; }
      bias[tid] = b;
    } else if (tid < 64 + NT) {
      int t = tid - 64;
      const float* ll = tp + t * PPT + 14343;  // leaf_logits [8][2]
      float d0[8], d1[8];
#pragma unroll
      for (int le = 0; le < 8; ++le) {
        float aa = ll[2 * le], bb2 = ll[2 * le + 1];
        float m = fmaxf(aa, bb2);
        float e0 = __expf(aa - m), e1 = __expf(bb2 - m);
        float inv = 1.0f / (e0 + e1);
        d0[le] = e0 * inv; d1[le] = e1 * inv;
      }
      float ww = tw[t];
      float* c = coef + t * 10;
      c[0] = ww * (d0[0] + d0[2] + d0[4] + d0[6]);
      c[1] = ww * (d1[0] + d1[2] + d1[4] + d1[6]);
      c[2] = ww * (d0[1] - d0[2]);
      c[3] = ww * (d1[1] - d1[2]);
      c[4] = ww * (d0[3] - d0[4]);
      c[5] = ww * (d1[3] - d1[4]);
      c[6] = ww * (d0[5] - d0[6]);
      c[7] = ww * (d1[5] - d1[6]);
      c[8] = ww * d0[7];
      c[9] = ww * d1[7];
    }
  }
}

// ---------------- asm helpers -------------------------------------------------
__device__ __forceinline__ f32x4 gload4(const float* p) {
  f32x4 r;
  asm volatile("global_load_dwordx4 %0, %1, off" : "=v"(r) : "v"(p) : "memory");
  return r;
}
__device__ __forceinline__ u32x4 dsread16(uint32_t addr) {
  u32x4 r;
  asm volatile("ds_read_b128 %0, %1" : "=v"(r) : "v"(addr) : "memory");
  return r;
}
__device__ __forceinline__ void stage16(const void* g, void* l) {
  __builtin_amdgcn_global_load_lds(
      (const __attribute__((address_space(1))) void*)g,
      (__attribute__((address_space(3))) void*)l, 16, 0, 0);
}

// One K-step (BK=64). Distance-3 protocol, 4 LDS bufs, 3 A-reg bufs:
//   top: vmcnt(WN) [drains s(t),A(t)]; barrier
//   ds_read 16 B-frags of buf[t%4]; cvt A(t)
//   lgkmcnt(0)  -> my reads of buf[(t)%4] done before anyone restages it
//   issue stage(t+3)->buf[(t+3)%4] + A(t+3)->RC (RC free after cvt)
//   24 MFMA
#define ITERATION(tt, BUF, RC, WN, ISSUE)                                      \
  {                                                                            \
    WAITV(WN); SCHEDB;                                                         \
    __builtin_amdgcn_s_barrier();                                              \
    const uint32_t bb = sbase + (BUF) * 16384 + l16;                           \
    u32x4 bfr[16];                                                             \
    _Pragma("unroll")                                                          \
    for (int q = 0; q < 16; ++q) bfr[q] = dsread16(bb + q * 1024);             \
    u32x4 ah0, al0, ah1, al1;                                                  \
    cvt8(RC[0], RC[1], ah0, al0);                                              \
    cvt8(RC[2], RC[3], ah1, al1);                                              \
    WAITL0; SCHEDB;                                                            \
    if (ISSUE) {                                                               \
      const int t3 = (tt) + 3;                                                 \
      const char* gsrc = bspb + (size_t)t3 * 16384 + w4096l16;                 \
      char* ldst = sBgen + (((BUF) + 3) & 3) * 16384 + w4096;                  \
      _Pragma("unroll")                                                        \
      for (int q = 0; q < 4; ++q) stage16(gsrc + q * 1024, ldst + q * 1024);   \
      const float* ap = xbase + t3 * 64;                                       \
      RC[0] = gload4(ap);      RC[1] = gload4(ap + 4);                         \
      RC[2] = gload4(ap + 32); RC[3] = gload4(ap + 36);                        \
    }                                                                          \
    _Pragma("unroll")                                                          \
    for (int f = 0; f < 4; ++f) {                                              \
      bf16x8 bh = __builtin_bit_cast(bf16x8, bfr[f * 2]);                      \
      bf16x8 bl = __builtin_bit_cast(bf16x8, bfr[f * 2 + 1]);                  \
      bf16x8 Ah = __builtin_bit_cast(bf16x8, ah0);                             \
      bf16x8 Al = __builtin_bit_cast(bf16x8, al0);                             \
      acc[f] = __builtin_amdgcn_mfma_f32_16x16x32_bf16(Ah, bh, acc[f], 0,0,0); \
      acc[f] = __builtin_amdgcn_mfma_f32_16x16x32_bf16(Al, bh, acc[f], 0,0,0); \
      acc[f] = __builtin_amdgcn_mfma_f32_16x16x32_bf16(Ah, bl, acc[f], 0,0,0); \
    }                                                                          \
    _Pragma("unroll")                                                          \
    for (int f = 0; f < 4; ++f) {                                              \
      bf16x8 bh = __builtin_bit_cast(bf16x8, bfr[8 + f * 2]);                  \
      bf16x8 bl = __builtin_bit_cast(bf16x8, bfr[8 + f * 2 + 1]);              \
      bf16x8 Ah = __builtin_bit_cast(bf16x8, ah1);                             \
      bf16x8 Al = __builtin_bit_cast(bf16x8, al1);                             \
      acc[f] = __builtin_amdgcn_mfma_f32_16x16x32_bf16(Ah, bh, acc[f], 0,0,0); \
      acc[f] = __builtin_amdgcn_mfma_f32_16x16x32_bf16(Al, bh, acc[f], 0,0,0); \
      acc[f] = __builtin_amdgcn_mfma_f32_16x16x32_bf16(Ah, bl, acc[f], 0,0,0); \
    }                                                                          \
  }

__global__ __launch_bounds__(256) void tree_fused(
    const float* __restrict__ x,
    const unsigned short* __restrict__ bsp,
    const float* __restrict__ bias,
    const float* __restrict__ coef,
    float* __restrict__ out)
{
  __shared__ __align__(1024) unsigned char sB[4 * 16384];   // B hi/lo quad buffer

  const int tid = threadIdx.x;
  const int w   = tid >> 6;        // wave 0..3
  const int l   = tid & 63;
  const int rl  = l & 15;
  const int g   = l >> 4;
  const int l16 = l * 16;
  const int w4096 = w * 4096;
  const int w4096l16 = w4096 + l16;

  const int rowTile = blockIdx.x * 64 + w * 16;
  const float* xbase = x + (size_t)(rowTile + rl) * D_IN + g * 8;
  const char* bspb = (const char*)bsp;
  char* sBgen = (char*)&sB[0];
  const uint32_t sbase = (uint32_t)(uintptr_t)sBgen;

  f32x4 acc[4] = {};
  f32x4 r0[4], r1[4], r2[4];       // A regs, index t%3

  // prologue: issue [s0,A0, s1,A1, s2,A2] -> 24 outstanding vmem ops
  {
#pragma unroll
    for (int s = 0; s < 3; ++s) {
      const char* gs = bspb + (size_t)s * 16384 + w4096l16;
      char* ld = sBgen + s * 16384 + w4096;
#pragma unroll
      for (int q = 0; q < 4; ++q) stage16(gs + q * 1024, ld + q * 1024);
      const float* ap = xbase + s * 64;
      f32x4* rr = (s == 0) ? r0 : (s == 1) ? r1 : r2;
      rr[0] = gload4(ap);      rr[1] = gload4(ap + 4);
      rr[2] = gload4(ap + 32); rr[3] = gload4(ap + 36);
    }
  }

  // main loop: period 12 (buf %4 x A-reg %3), iters 0..23
  for (int tb = 0; tb < 24; tb += 12) {
    ITERATION(tb + 0,  0, r0, 16, 1);
    ITERATION(tb + 1,  1, r1, 16, 1);
    ITERATION(tb + 2,  2, r2, 16, 1);
    ITERATION(tb + 3,  3, r0, 16, 1);
    ITERATION(tb + 4,  0, r1, 16, 1);
    ITERATION(tb + 5,  1, r2, 16, 1);
    ITERATION(tb + 6,  2, r0, 16, 1);
    ITERATION(tb + 7,  3, r1, 16, 1);
    ITERATION(tb + 8,  0, r2, 16, 1);
    ITERATION(tb + 9,  1, r0, 16, 1);
    ITERATION(tb + 10, 2, r1, 16, 1);
    ITERATION(tb + 11, 3, r2, 16, 1);
  }
  // tail: issues stop once t+3 > 31
  ITERATION(24, 0, r0, 16, 1);
  ITERATION(25, 1, r1, 16, 1);
  ITERATION(26, 2, r2, 16, 1);
  ITERATION(27, 3, r0, 16, 1);
  ITERATION(28, 0, r1, 16, 1);
  ITERATION(29, 1, r2, 16, 0);
  ITERATION(30, 2, r0,  8, 0);
  ITERATION(31, 3, r1,  0, 0);

  // ---- epilogue: reuse buf0/buf1 LDS as strips (all reads of those bufs done) ----
  float (*strips)[16][65] = (float (*)[16][65])sBgen;   // 4*16*65*4 = 16640 B
#pragma unroll
  for (int f = 0; f < 4; ++f)
#pragma unroll
    for (int r = 0; r < 4; ++r)
      strips[w][4 * g + r][16 * f + rl] = acc[f][r];
  WAITL0;

  float o0 = 0.0f, o1 = 0.0f;
#pragma unroll
  for (int jt = 0; jt < 4; ++jt) {
    int t = g + 4 * jt;
    if (t < NT) {
      const float* cf = coef + t * 10;
      float dd[4];
#pragma unroll
      for (int i = 0; i < 4; ++i) {
        float z = strips[w][rl][4 * t + i] + bias[4 * t + i];
        dd[i] = 1.0f / (1.0f + __expf(-z));
      }
      float s = 1.0f / (4.0f + dd[3] + 1e-8f);
      o0 += s * (cf[0] + dd[0] * cf[2] + dd[1] * cf[4] + dd[2] * cf[6] + dd[3] * cf[8]);
      o1 += s * (cf[1] + dd[0] * cf[3] + dd[1] * cf[5] + dd[2] * cf[7] + dd[3] * cf[9]);
    }
  }
  o0 += __shfl_xor(o0, 16); o0 += __shfl_xor(o0, 32);
  o1 += __shfl_xor(o1, 16); o1 += __shfl_xor(o1, 32);
  if (l < 16) {
    ((float2*)out)[rowTile + rl] = make_float2(o0, o1);
  }
}

// ---------------- launch ------------------------------------------------------
extern "C" void kernel_launch(void* const* d_in, const int* in_sizes, int n_in,
                              void* d_out, int out_size, void* d_ws, size_t ws_size,
                              hipStream_t stream) {
  (void)in_sizes; (void)n_in; (void)out_size; (void)ws_size;
  const float* x  = (const float*)d_in[0];
  const float* tp = (const float*)d_in[1];
  const float* tw = (const float*)d_in[2];
  float* out = (float*)d_out;

  unsigned short* bsp = (unsigned short*)d_ws;                    // 524288 B
  float* bias = (float*)((char*)d_ws + 524288);                   // 256 B
  float* coef = (float*)((char*)d_ws + 524288 + 256);             // 600 B

  prep_split<<<64, 256, 0, stream>>>(tp, tw, bsp, bias, coef);
  tree_fused<<<512, 256, 0, stream>>>(x, bsp, bias, coef, out);
}